// Round 4
// baseline (215.990 us; speedup 1.0000x reference)
//
#include <hip/hip_runtime.h>

#define SEQ_T 2048
#define NHEAD 16

typedef unsigned short u16;
typedef __attribute__((ext_vector_type(4))) float f32x4;
typedef __attribute__((ext_vector_type(8))) short short8;
typedef __attribute__((ext_vector_type(4))) unsigned short u16x4;

__device__ __forceinline__ u16 f2bf(float f) {
  unsigned u = __float_as_uint(f);
  unsigned r = (u + 0x7FFFu + ((u >> 16) & 1u)) >> 16;
  return (u16)r;
}

__device__ __forceinline__ void gload_lds16(const void* g, void* l) {
  __builtin_amdgcn_global_load_lds((const __attribute__((address_space(1))) void*)g,
                                   (__attribute__((address_space(3))) void*)l, 16, 0, 0);
}

// sigmoid with 1 trans op: exp2 + Newton-rcp (seed err ~5%, 1 step -> ~0.3%)
__device__ __forceinline__ float sigfast(float s) {
  const float e = __builtin_amdgcn_exp2f(s);
  const float d = 1.0f + e;
  float y = __uint_as_float(0x7EF311C3u - __float_as_uint(d));
  return y * __builtin_fmaf(-d, y, 2.0f);
}

// ---------------------------------------------------------------- convert
__global__ __launch_bounds__(256) void cvt_all(
    const float* __restrict__ x, const float* __restrict__ wq, const float* __restrict__ wk,
    const float* __restrict__ wv, const float* __restrict__ wo,
    u16* __restrict__ xb, u16* __restrict__ wqb, u16* __restrict__ wkb,
    u16* __restrict__ wvb, u16* __restrict__ wob) {
  const int bid = blockIdx.x;
  const float* s; u16* d; int base;
  if (bid < 4096) { s = x; d = xb; base = bid; }
  else {
    const int w = (bid - 4096) >> 10;
    base = (bid - 4096) & 1023;
    if (w == 0)      { s = wq; d = wqb; }
    else if (w == 1) { s = wk; d = wkb; }
    else if (w == 2) { s = wv; d = wvb; }
    else             { s = wo; d = wob; }
  }
  const int i = base * 256 + threadIdx.x;
  const float4 v = ((const float4*)s)[i];
  u16x4 o;
  o[0] = f2bf(v.x); o[1] = f2bf(v.y); o[2] = f2bf(v.z); o[3] = f2bf(v.w);
  ((u16x4*)d)[i] = o;
}

// ------------------------------------------------- shared GEMM main loop (128x128)
// 3-buffer, prefetch distance 2, counted vmcnt (T4): never drain to 0 in loop.
static __device__ __forceinline__ void gemm_core(
    const u16* __restrict__ A, const u16* __restrict__ Bmat,
    u16* lds, int row0, int col0, int tid, f32x4 acc[4][4]) {
  const int wv = tid >> 6, lane = tid & 63;
  const int wr = wv >> 1, wc = wv & 1;
  const int lr15 = lane & 15, lg = lane >> 4;
  const int r = tid >> 2, c = tid & 3;
  const int sc = c ^ (r & 3);                 // (r+64 == r mod 4 -> same swizzle)

  auto stage = [&](int buf, int kt) {
    const int k0 = kt * 32;
    const u16* gA = A    + (size_t)(row0 + r) * 1024 + k0 + sc * 8;
    const u16* gB = Bmat + (size_t)(col0 + r) * 1024 + k0 + sc * 8;
    u16* base = lds + buf * 8192;
    gload_lds16(gA,             base + wv * 512);
    gload_lds16(gA + 64 * 1024, base + 2048 + wv * 512);
    gload_lds16(gB,             base + 4096 + wv * 512);
    gload_lds16(gB + 64 * 1024, base + 6144 + wv * 512);
  };

  auto compute = [&](int buf) {
    const u16* lA = lds + buf * 8192;
    const u16* lB = lA + 4096;
    short8 a[4], b[4];
#pragma unroll
    for (int m = 0; m < 4; ++m) {
      const int row = wr * 64 + m * 16 + lr15;
      a[m] = *(const short8*)(lA + row * 32 + (lg ^ (row & 3)) * 8);
    }
#pragma unroll
    for (int n = 0; n < 4; ++n) {
      const int row = wc * 64 + n * 16 + lr15;
      b[n] = *(const short8*)(lB + row * 32 + (lg ^ (row & 3)) * 8);
    }
    __builtin_amdgcn_s_setprio(1);
#pragma unroll
    for (int m = 0; m < 4; ++m)
#pragma unroll
      for (int n = 0; n < 4; ++n)
        acc[m][n] = __builtin_amdgcn_mfma_f32_16x16x32_bf16(a[m], b[n], acc[m][n], 0, 0, 0);
    __builtin_amdgcn_s_setprio(0);
  };

  stage(0, 0); stage(1, 1);
  asm volatile("s_waitcnt vmcnt(4)" ::: "memory");
  __builtin_amdgcn_s_barrier();
  asm volatile("" ::: "memory");
  int cur = 0;
  for (int t = 0; t < 30; ++t) {
    stage(cur >= 1 ? cur - 1 : 2, t + 2);     // (cur+2)%3
    compute(cur);
    __builtin_amdgcn_sched_barrier(0);
    asm volatile("s_waitcnt vmcnt(4) lgkmcnt(0)" ::: "memory");
    __builtin_amdgcn_s_barrier();
    asm volatile("" ::: "memory");
    cur = cur >= 2 ? 0 : cur + 1;
  }
  compute(cur);
  __builtin_amdgcn_sched_barrier(0);
  asm volatile("s_waitcnt vmcnt(0) lgkmcnt(0)" ::: "memory");
  __builtin_amdgcn_s_barrier();
  asm volatile("" ::: "memory");
  cur = cur >= 2 ? 0 : cur + 1;
  compute(cur);
}

// ---------------------------------------------------- fused QKV projection
// Q is additionally scaled by -0.125*log2(e) so attn sigmoid = rcp(1+exp2(s)).
__global__ __launch_bounds__(256) void gemm_qkv(
    const u16* __restrict__ X,
    const u16* __restrict__ WQ, const u16* __restrict__ WK, const u16* __restrict__ WV,
    const float* __restrict__ BQ, const float* __restrict__ BK, const float* __restrict__ BV,
    u16* __restrict__ OQ, u16* __restrict__ OK, u16* __restrict__ OV) {
  __shared__ u16 lds[3 * 8192];
  const int which = blockIdx.x >> 3;
  const int col0 = (blockIdx.x & 7) * 128;
  const int row0 = blockIdx.y * 128;
  const u16* W = (which == 0) ? WQ : ((which == 1) ? WK : WV);
  const float* bias = (which == 0) ? BQ : ((which == 1) ? BK : BV);
  u16* out = (which == 0) ? OQ : ((which == 1) ? OK : OV);
  const int tid = threadIdx.x;
  f32x4 acc[4][4];
#pragma unroll
  for (int m = 0; m < 4; ++m)
#pragma unroll
    for (int n = 0; n < 4; ++n) acc[m][n] = (f32x4){0.f, 0.f, 0.f, 0.f};

  gemm_core(X, W, lds, row0, col0, tid, acc);

  const float qscale = (which == 0) ? -0.18033688011112042f : 1.0f;
  const int wv = tid >> 6, lane = tid & 63;
  const int wr = wv >> 1, wc = wv & 1;
#pragma unroll
  for (int n = 0; n < 4; ++n) {
    const int col = col0 + wc * 64 + n * 16 + (lane & 15);
    const float bc = bias[col];
    const int hh = col >> 6, hd = col & 63;
#pragma unroll
    for (int m = 0; m < 4; ++m) {
#pragma unroll
      for (int r = 0; r < 4; ++r) {
        const int row = row0 + wr * 64 + m * 16 + (lane >> 4) * 4 + r;
        const int b_ = row >> 11, tt = row & 2047;
        const u16 h = f2bf((acc[m][n][r] + bc) * qscale);
        if (which != 2) {
          out[(((size_t)(b_ * NHEAD + hh) * SEQ_T + tt) << 6) + hd] = h;
        } else {
          out[(((size_t)(b_ * NHEAD + hh) << 6) + hd) * SEQ_T + tt] = h;
        }
      }
    }
  }
}

// ------------------------------------------------------ sigmoid attention
// grid (16, 32): 4 waves x 32 q-rows (2 independent 16-row groups per wave).
// Swapped QK^T with sigma-permuted K rows; sigmoid packs in-register into the
// PV A-fragment (no P-LDS). K/V frags loaded once, used by both groups.
__device__ __forceinline__ int sigp(int u) {
  return (u & 35) | ((u & 8) << 1) | ((u & 4) << 1) | ((u & 16) >> 2);
}

__global__ __launch_bounds__(256) void attn_sig(
    const u16* __restrict__ Q, const u16* __restrict__ K,
    const u16* __restrict__ Vt, u16* __restrict__ AO) {
  __shared__ u16 ldsK[2][4096];   // [64 s(perm)][64 hd], chunk^(row&7) swizzle
  __shared__ u16 ldsV[2][4096];   // [64 hd][64 s], same swizzle
  const int tid = threadIdx.x, wv = tid >> 6, lane = tid & 63;
  const int lr15 = lane & 15, lg = lane >> 4;
  const int bh = blockIdx.y;
  const int qw0 = blockIdx.x * 128 + wv * 32;
  const u16* Qb = Q  + (size_t)bh * SEQ_T * 64;
  const u16* Kb = K  + (size_t)bh * SEQ_T * 64;
  const u16* Vb = Vt + (size_t)bh * 64 * SEQ_T;

  short8 qf[2][2];
#pragma unroll
  for (int g = 0; g < 2; ++g)
#pragma unroll
    for (int kk = 0; kk < 2; ++kk)
      qf[g][kk] = *(const short8*)(Qb + (size_t)(qw0 + g * 16 + lr15) * 64 + kk * 32 + lg * 8);

  short8 onesf;
#pragma unroll
  for (int i = 0; i < 8; ++i) onesf[i] = (short)0x3F80;

  f32x4 oacc[2][4];
#pragma unroll
  for (int g = 0; g < 2; ++g)
#pragma unroll
    for (int n = 0; n < 4; ++n) oacc[g][n] = (f32x4){0.f, 0.f, 0.f, 0.f};
  f32x4 dacc[2];
  dacc[0] = (f32x4){0.f, 0.f, 0.f, 0.f};
  dacc[1] = (f32x4){0.f, 0.f, 0.f, 0.f};

  const int r0 = tid >> 3, c0 = tid & 7;
  const int sc0 = c0 ^ (r0 & 7);
  const int sg0 = sigp(r0);            // sigma(r0+32) = sigma(r0)+32

  auto stage = [&](int buf, int s0) {
    gload_lds16(Kb + (size_t)(s0 + sg0) * 64 + sc0 * 8,        &ldsK[buf][wv * 512]);
    gload_lds16(Vb + (size_t)r0 * SEQ_T + s0 + sc0 * 8,        &ldsV[buf][wv * 512]);
    gload_lds16(Kb + (size_t)(s0 + sg0 + 32) * 64 + sc0 * 8,   &ldsK[buf][2048 + wv * 512]);
    gload_lds16(Vb + (size_t)(r0 + 32) * SEQ_T + s0 + sc0 * 8, &ldsV[buf][2048 + wv * 512]);
  };

  stage(0, 0);
  __syncthreads();

  for (int st = 0; st < 32; ++st) {
    if (st < 31) stage((st + 1) & 1, (st + 1) * 64);
    const u16* lK = ldsK[st & 1];
    const u16* lV = ldsV[st & 1];

    // S^T = K(perm) . Q^T for both q-groups; K frags shared
    f32x4 sacc[2][4];
#pragma unroll
    for (int g = 0; g < 2; ++g)
#pragma unroll
      for (int n = 0; n < 4; ++n) sacc[g][n] = (f32x4){0.f, 0.f, 0.f, 0.f};
    __builtin_amdgcn_s_setprio(1);
#pragma unroll
    for (int kk = 0; kk < 2; ++kk) {
#pragma unroll
      for (int n = 0; n < 4; ++n) {
        const int row = n * 16 + lr15;
        const short8 kfn = *(const short8*)(lK + row * 64 + (((kk * 4 + lg) ^ (row & 7)) * 8));
        sacc[0][n] = __builtin_amdgcn_mfma_f32_16x16x32_bf16(kfn, qf[0][kk], sacc[0][n], 0, 0, 0);
        sacc[1][n] = __builtin_amdgcn_mfma_f32_16x16x32_bf16(kfn, qf[1][kk], sacc[1][n], 0, 0, 0);
      }
    }
    __builtin_amdgcn_s_setprio(0);

    // sigmoid (1 trans/score) -> pack straight into PV A-frags
    short8 pf[2][2];
#pragma unroll
    for (int g = 0; g < 2; ++g) {
      unsigned w[8];
#pragma unroll
      for (int n = 0; n < 4; ++n) {
        const float g0 = sigfast(sacc[g][n][0]);
        const float g1 = sigfast(sacc[g][n][1]);
        const float g2 = sigfast(sacc[g][n][2]);
        const float g3 = sigfast(sacc[g][n][3]);
        asm("v_cvt_pk_bf16_f32 %0, %1, %2" : "=v"(w[n * 2 + 0]) : "v"(g0), "v"(g1));
        asm("v_cvt_pk_bf16_f32 %0, %1, %2" : "=v"(w[n * 2 + 1]) : "v"(g2), "v"(g3));
      }
      union { unsigned u[4]; short8 s8; } c0v, c1v;
      c0v.u[0] = w[0]; c0v.u[1] = w[1]; c0v.u[2] = w[2]; c0v.u[3] = w[3];
      c1v.u[0] = w[4]; c1v.u[1] = w[5]; c1v.u[2] = w[6]; c1v.u[3] = w[7];
      pf[g][0] = c0v.s8; pf[g][1] = c1v.s8;
    }

    // O += P.V ; den += P.1 ; V frags shared between groups
    __builtin_amdgcn_s_setprio(1);
#pragma unroll
    for (int kk = 0; kk < 2; ++kk) {
#pragma unroll
      for (int m = 0; m < 4; ++m) {
        const int vr = m * 16 + lr15;
        const short8 vfm = *(const short8*)(lV + vr * 64 + (((kk * 4 + lg) ^ (vr & 7)) * 8));
        oacc[0][m] = __builtin_amdgcn_mfma_f32_16x16x32_bf16(pf[0][kk], vfm, oacc[0][m], 0, 0, 0);
        oacc[1][m] = __builtin_amdgcn_mfma_f32_16x16x32_bf16(pf[1][kk], vfm, oacc[1][m], 0, 0, 0);
      }
      dacc[0] = __builtin_amdgcn_mfma_f32_16x16x32_bf16(pf[0][kk], onesf, dacc[0], 0, 0, 0);
      dacc[1] = __builtin_amdgcn_mfma_f32_16x16x32_bf16(pf[1][kk], onesf, dacc[1], 0, 0, 0);
    }
    __builtin_amdgcn_s_setprio(0);
    __syncthreads();
  }

  const int b_ = bh >> 4, hh = bh & 15;
#pragma unroll
  for (int g = 0; g < 2; ++g) {
    f32x4 rden;
#pragma unroll
    for (int r = 0; r < 4; ++r) rden[r] = __builtin_amdgcn_rcpf(dacc[g][r] + 1e-6f);
#pragma unroll
    for (int n = 0; n < 4; ++n) {
      const int hd = n * 16 + lr15;
#pragma unroll
      for (int r = 0; r < 4; ++r) {
        const int tt = qw0 + g * 16 + lg * 4 + r;
        AO[((size_t)(b_ * SEQ_T + tt) << 10) + hh * 64 + hd] = f2bf(oacc[g][n][r] * rden[r]);
      }
    }
  }
}

// ------------------------------------------- output projection + residual
// 64x128 tile; 3-buffer counted-vmcnt pipeline (3 loads/thread -> vmcnt(3)).
__global__ __launch_bounds__(256) void gemm_out(
    const u16* __restrict__ A, const u16* __restrict__ W,
    const float* __restrict__ bias, const float* __restrict__ X,
    const float* __restrict__ alphap, float* __restrict__ out) {
  __shared__ u16 lds[3 * 6144];   // per buf: A 64x32 (2048) + B 128x32 (4096)
  const int col0 = blockIdx.x * 128, row0 = blockIdx.y * 64;
  const int tid = threadIdx.x, wv = tid >> 6, lane = tid & 63;
  const int lr15 = lane & 15, lg = lane >> 4;
  const int r = tid >> 2, c = tid & 3;
  const int sc = c ^ (r & 3);
  f32x4 acc[4][2];
#pragma unroll
  for (int m = 0; m < 4; ++m)
#pragma unroll
    for (int n = 0; n < 2; ++n) acc[m][n] = (f32x4){0.f, 0.f, 0.f, 0.f};

  auto stage = [&](int buf, int kt) {
    const int k0 = kt * 32;
    u16* base = lds + buf * 6144;
    gload_lds16(A + (size_t)(row0 + r) * 1024 + k0 + sc * 8, base + wv * 512);
    const u16* gB = W + (size_t)(col0 + r) * 1024 + k0 + sc * 8;
    gload_lds16(gB,             base + 2048 + wv * 512);
    gload_lds16(gB + 64 * 1024, base + 4096 + wv * 512);
  };

  auto compute = [&](int buf) {
    const u16* lA = lds + buf * 6144;
    const u16* lB = lA + 2048;
    short8 a[4], b[2];
#pragma unroll
    for (int m = 0; m < 4; ++m) {
      const int row = m * 16 + lr15;
      a[m] = *(const short8*)(lA + row * 32 + (lg ^ (row & 3)) * 8);
    }
#pragma unroll
    for (int n = 0; n < 2; ++n) {
      const int row = wv * 32 + n * 16 + lr15;
      b[n] = *(const short8*)(lB + row * 32 + (lg ^ (row & 3)) * 8);
    }
    __builtin_amdgcn_s_setprio(1);
#pragma unroll
    for (int m = 0; m < 4; ++m)
#pragma unroll
      for (int n = 0; n < 2; ++n)
        acc[m][n] = __builtin_amdgcn_mfma_f32_16x16x32_bf16(a[m], b[n], acc[m][n], 0, 0, 0);
    __builtin_amdgcn_s_setprio(0);
  };

  stage(0, 0); stage(1, 1);
  asm volatile("s_waitcnt vmcnt(3)" ::: "memory");
  __builtin_amdgcn_s_barrier();
  asm volatile("" ::: "memory");
  int cur = 0;
  for (int t = 0; t < 30; ++t) {
    stage(cur >= 1 ? cur - 1 : 2, t + 2);
    compute(cur);
    __builtin_amdgcn_sched_barrier(0);
    asm volatile("s_waitcnt vmcnt(3) lgkmcnt(0)" ::: "memory");
    __builtin_amdgcn_s_barrier();
    asm volatile("" ::: "memory");
    cur = cur >= 2 ? 0 : cur + 1;
  }
  compute(cur);
  __builtin_amdgcn_sched_barrier(0);
  asm volatile("s_waitcnt vmcnt(0) lgkmcnt(0)" ::: "memory");
  __builtin_amdgcn_s_barrier();
  asm volatile("" ::: "memory");
  cur = cur >= 2 ? 0 : cur + 1;
  compute(cur);

  const float alpha = alphap[0];
#pragma unroll
  for (int n = 0; n < 2; ++n) {
    const int col = col0 + wv * 32 + n * 16 + lr15;
    const float bc = bias[col];
#pragma unroll
    for (int m = 0; m < 4; ++m) {
#pragma unroll
      for (int rr = 0; rr < 4; ++rr) {
        const int row = row0 + m * 16 + lg * 4 + rr;
        const size_t off = ((size_t)row << 10) + col;
        out[off] = X[off] + alpha * (acc[m][n][rr] + bc);
      }
    }
  }
}

// ------------------------------------------------------------------ launch
extern "C" void kernel_launch(void* const* d_in, const int* in_sizes, int n_in,
                              void* d_out, int out_size, void* d_ws, size_t ws_size,
                              hipStream_t stream) {
  const float* x  = (const float*)d_in[0];
  const float* wq = (const float*)d_in[1];
  const float* bq = (const float*)d_in[2];
  const float* wk = (const float*)d_in[3];
  const float* bk = (const float*)d_in[4];
  const float* wv = (const float*)d_in[5];
  const float* bv = (const float*)d_in[6];
  const float* wo = (const float*)d_in[7];
  const float* bo = (const float*)d_in[8];
  const float* alpha = (const float*)d_in[9];
  float* out = (float*)d_out;
  char* ws = (char*)d_ws;
  const size_t MB = 1u << 20;
  u16* xb  = (u16*)(ws + 0 * MB);
  u16* wqb = (u16*)(ws + 8 * MB);
  u16* wkb = (u16*)(ws + 10 * MB);
  u16* wvb = (u16*)(ws + 12 * MB);
  u16* wob = (u16*)(ws + 14 * MB);
  u16* qw  = (u16*)(ws + 16 * MB);   // [B,H,T,64] (scaled by -log2e/8)
  u16* kw  = (u16*)(ws + 24 * MB);   // [B,H,T,64]
  u16* vtw = (u16*)(ws + 32 * MB);   // [B,H,64,T]
  u16* aow = (u16*)(ws + 40 * MB);   // [4096,1024]

  cvt_all<<<8192, 256, 0, stream>>>(x, wq, wk, wv, wo, xb, wqb, wkb, wvb, wob);
  gemm_qkv<<<dim3(24, 32), 256, 0, stream>>>(xb, wqb, wkb, wvb, bq, bk, bv, qw, kw, vtw);
  attn_sig<<<dim3(16, 32), 256, 0, stream>>>(qw, kw, vtw, aow);
  gemm_out<<<dim3(8, 64), 256, 0, stream>>>(aow, wob, bo, x, alpha, out);
}

// Round 5
// 198.462 us; speedup vs baseline: 1.0883x; 1.0883x over previous
//
#include <hip/hip_runtime.h>

#define SEQ_T 2048
#define NHEAD 16

typedef unsigned short u16;
typedef __attribute__((ext_vector_type(4))) float f32x4;
typedef __attribute__((ext_vector_type(8))) short short8;
typedef __attribute__((ext_vector_type(4))) unsigned short u16x4;

__device__ __forceinline__ u16 f2bf(float f) {
  unsigned u = __float_as_uint(f);
  unsigned r = (u + 0x7FFFu + ((u >> 16) & 1u)) >> 16;
  return (u16)r;
}

__device__ __forceinline__ void gload_lds16(const void* g, void* l) {
  __builtin_amdgcn_global_load_lds((const __attribute__((address_space(1))) void*)g,
                                   (__attribute__((address_space(3))) void*)l, 16, 0, 0);
}

// sigmoid with 1 trans op: exp2 + Newton-rcp (seed err ~5%, 1 step -> ~0.3%)
__device__ __forceinline__ float sigfast(float s) {
  const float e = __builtin_amdgcn_exp2f(s);
  const float d = 1.0f + e;
  float y = __uint_as_float(0x7EF311C3u - __float_as_uint(d));
  return y * __builtin_fmaf(-d, y, 2.0f);
}

// ---------------------------------------------------------------- convert
__global__ __launch_bounds__(256) void cvt_all(
    const float* __restrict__ x, const float* __restrict__ wq, const float* __restrict__ wk,
    const float* __restrict__ wv, const float* __restrict__ wo,
    u16* __restrict__ xb, u16* __restrict__ wqb, u16* __restrict__ wkb,
    u16* __restrict__ wvb, u16* __restrict__ wob) {
  const int bid = blockIdx.x;
  const float* s; u16* d; int base;
  if (bid < 4096) { s = x; d = xb; base = bid; }
  else {
    const int w = (bid - 4096) >> 10;
    base = (bid - 4096) & 1023;
    if (w == 0)      { s = wq; d = wqb; }
    else if (w == 1) { s = wk; d = wkb; }
    else if (w == 2) { s = wv; d = wvb; }
    else             { s = wo; d = wob; }
  }
  const int i = base * 256 + threadIdx.x;
  const float4 v = ((const float4*)s)[i];
  u16x4 o;
  o[0] = f2bf(v.x); o[1] = f2bf(v.y); o[2] = f2bf(v.z); o[3] = f2bf(v.w);
  ((u16x4*)d)[i] = o;
}

// ------------------------------------------------- 8-wave GEMM core (128x128)
// 512 threads = 8 waves in 2x4; wave output 64x32. 3-buffer counted-vmcnt:
// stage(t+2) -> compute(t) -> vmcnt(2) [t+1 landed] -> barrier. No drains.
static __device__ __forceinline__ void gemm_core8(
    const u16* __restrict__ A, const u16* __restrict__ Bmat,
    u16* lds, int row0, int col0, int tid, f32x4 acc[4][2]) {
  const int wv = tid >> 6, lane = tid & 63;
  const int wr = wv >> 2, wc = wv & 3;
  const int lr15 = lane & 15, lg = lane >> 4;
  const int r = tid >> 2, c = tid & 3;
  const int sc = c ^ (r & 3);

  auto stage = [&](int buf, int kt) {
    const int k0 = kt * 32;
    u16* base = lds + buf * 8192;
    gload_lds16(A    + (size_t)(row0 + r) * 1024 + k0 + sc * 8, base + wv * 512);
    gload_lds16(Bmat + (size_t)(col0 + r) * 1024 + k0 + sc * 8, base + 4096 + wv * 512);
  };

  auto compute = [&](int buf) {
    const u16* lA = lds + buf * 8192;
    const u16* lB = lA + 4096;
    short8 a[4], b[2];
#pragma unroll
    for (int m = 0; m < 4; ++m) {
      const int row = wr * 64 + m * 16 + lr15;
      a[m] = *(const short8*)(lA + row * 32 + (lg ^ (row & 3)) * 8);
    }
#pragma unroll
    for (int n = 0; n < 2; ++n) {
      const int row = wc * 32 + n * 16 + lr15;
      b[n] = *(const short8*)(lB + row * 32 + (lg ^ (row & 3)) * 8);
    }
    __builtin_amdgcn_s_setprio(1);
#pragma unroll
    for (int m = 0; m < 4; ++m)
#pragma unroll
      for (int n = 0; n < 2; ++n)
        acc[m][n] = __builtin_amdgcn_mfma_f32_16x16x32_bf16(a[m], b[n], acc[m][n], 0, 0, 0);
    __builtin_amdgcn_s_setprio(0);
  };

  stage(0, 0); stage(1, 1);
  asm volatile("s_waitcnt vmcnt(2)" ::: "memory");
  __builtin_amdgcn_s_barrier();
  asm volatile("" ::: "memory");
  int cur = 0;
  for (int t = 0; t < 30; ++t) {
    stage(cur == 0 ? 2 : cur - 1, t + 2);    // buf (t+2)%3
    compute(cur);
    __builtin_amdgcn_sched_barrier(0);
    asm volatile("s_waitcnt vmcnt(2) lgkmcnt(0)" ::: "memory");
    __builtin_amdgcn_s_barrier();
    asm volatile("" ::: "memory");
    cur = cur == 2 ? 0 : cur + 1;
  }
  compute(cur);
  __builtin_amdgcn_sched_barrier(0);
  asm volatile("s_waitcnt vmcnt(0) lgkmcnt(0)" ::: "memory");
  __builtin_amdgcn_s_barrier();
  asm volatile("" ::: "memory");
  cur = cur == 2 ? 0 : cur + 1;
  compute(cur);
}

// ---------------------------------------------------- fused QKV projection
// Q is additionally scaled by -0.125*log2(e) so attn sigmoid = rcp(1+exp2(s)).
__global__ __launch_bounds__(512) void gemm_qkv(
    const u16* __restrict__ X,
    const u16* __restrict__ WQ, const u16* __restrict__ WK, const u16* __restrict__ WV,
    const float* __restrict__ BQ, const float* __restrict__ BK, const float* __restrict__ BV,
    u16* __restrict__ OQ, u16* __restrict__ OK, u16* __restrict__ OV) {
  __shared__ u16 lds[3 * 8192];
  const int which = blockIdx.x >> 3;
  const int col0 = (blockIdx.x & 7) * 128;
  const int row0 = blockIdx.y * 128;
  const u16* W = (which == 0) ? WQ : ((which == 1) ? WK : WV);
  const float* bias = (which == 0) ? BQ : ((which == 1) ? BK : BV);
  u16* out = (which == 0) ? OQ : ((which == 1) ? OK : OV);
  const int tid = threadIdx.x;
  f32x4 acc[4][2];
#pragma unroll
  for (int m = 0; m < 4; ++m)
#pragma unroll
    for (int n = 0; n < 2; ++n) acc[m][n] = (f32x4){0.f, 0.f, 0.f, 0.f};

  gemm_core8(X, W, lds, row0, col0, tid, acc);

  const float qscale = (which == 0) ? -0.18033688011112042f : 1.0f;
  const int wv = tid >> 6, lane = tid & 63;
  const int wr = wv >> 2, wc = wv & 3;
  const int lr15 = lane & 15, lg = lane >> 4;
#pragma unroll
  for (int n = 0; n < 2; ++n) {
    const int col = col0 + wc * 32 + n * 16 + lr15;
    const float bc = bias[col];
    const int hh = col >> 6, hd = col & 63;
#pragma unroll
    for (int m = 0; m < 4; ++m) {
#pragma unroll
      for (int r = 0; r < 4; ++r) {
        const int row = row0 + wr * 64 + m * 16 + lg * 4 + r;
        const int b_ = row >> 11, tt = row & 2047;
        const u16 h = f2bf((acc[m][n][r] + bc) * qscale);
        if (which != 2) {
          out[(((size_t)(b_ * NHEAD + hh) * SEQ_T + tt) << 6) + hd] = h;
        } else {
          out[(((size_t)(b_ * NHEAD + hh) << 6) + hd) * SEQ_T + tt] = h;
        }
      }
    }
  }
}

// ------------------------------------------------------ sigmoid attention
// grid (16, 32): 8 waves x 16 q-rows = 128 q/block; 512 blocks = 2/CU (4 w/SIMD).
// Swapped QK^T with sigma-permuted K rows; sigmoid packs in-register into the
// PV A-fragment (no P-LDS). 3-buffer counted-vmcnt K/V staging (no drains).
__device__ __forceinline__ int sigp(int u) {
  return (u & 35) | ((u & 8) << 1) | ((u & 4) << 1) | ((u & 16) >> 2);
}

__global__ __launch_bounds__(512) void attn_sig(
    const u16* __restrict__ Q, const u16* __restrict__ K,
    const u16* __restrict__ Vt, u16* __restrict__ AO) {
  __shared__ u16 lds[3 * 8192];   // per buf: K[64 s(perm)][64 hd], V[64 hd][64 s]
  const int tid = threadIdx.x, wv = tid >> 6, lane = tid & 63;
  const int lr15 = lane & 15, lg = lane >> 4;
  const int bh = blockIdx.y;
  const int q0 = blockIdx.x * 128 + wv * 16;
  const u16* Qb = Q  + (size_t)bh * SEQ_T * 64;
  const u16* Kb = K  + (size_t)bh * SEQ_T * 64;
  const u16* Vb = Vt + (size_t)bh * 64 * SEQ_T;

  short8 qf[2];
#pragma unroll
  for (int kk = 0; kk < 2; ++kk)
    qf[kk] = *(const short8*)(Qb + (size_t)(q0 + lr15) * 64 + kk * 32 + lg * 8);
  asm volatile("s_waitcnt vmcnt(0)" ::: "memory");   // clean vm counter

  short8 onesf;
#pragma unroll
  for (int i = 0; i < 8; ++i) onesf[i] = (short)0x3F80;

  f32x4 oacc[4];
#pragma unroll
  for (int n = 0; n < 4; ++n) oacc[n] = (f32x4){0.f, 0.f, 0.f, 0.f};
  f32x4 dacc = (f32x4){0.f, 0.f, 0.f, 0.f};

  const int r0 = tid >> 3, c0 = tid & 7;    // 512 threads cover 64 rows x 8 chunks
  const int sc0 = c0 ^ (r0 & 7);
  const int sg0 = sigp(r0);

  auto stage = [&](int buf, int s0) {
    gload_lds16(Kb + (size_t)(s0 + sg0) * 64 + sc0 * 8,  lds + buf * 8192 + wv * 512);
    gload_lds16(Vb + (size_t)r0 * SEQ_T + s0 + sc0 * 8,  lds + buf * 8192 + 4096 + wv * 512);
  };

  auto compute = [&](int buf) {
    const u16* lK = lds + buf * 8192;
    const u16* lV = lK + 4096;
    f32x4 sacc[4];
#pragma unroll
    for (int n = 0; n < 4; ++n) sacc[n] = (f32x4){0.f, 0.f, 0.f, 0.f};
    __builtin_amdgcn_s_setprio(1);
#pragma unroll
    for (int kk = 0; kk < 2; ++kk) {
#pragma unroll
      for (int n = 0; n < 4; ++n) {
        const int row = n * 16 + lr15;
        const short8 kf = *(const short8*)(lK + row * 64 + (((kk * 4 + lg) ^ (row & 7)) * 8));
        sacc[n] = __builtin_amdgcn_mfma_f32_16x16x32_bf16(kf, qf[kk], sacc[n], 0, 0, 0);
      }
    }
    __builtin_amdgcn_s_setprio(0);

    unsigned w[8];
#pragma unroll
    for (int n = 0; n < 4; ++n) {
      const float g0 = sigfast(sacc[n][0]);
      const float g1 = sigfast(sacc[n][1]);
      const float g2 = sigfast(sacc[n][2]);
      const float g3 = sigfast(sacc[n][3]);
      asm("v_cvt_pk_bf16_f32 %0, %1, %2" : "=v"(w[n * 2 + 0]) : "v"(g0), "v"(g1));
      asm("v_cvt_pk_bf16_f32 %0, %1, %2" : "=v"(w[n * 2 + 1]) : "v"(g2), "v"(g3));
    }
    union { unsigned u[4]; short8 s8; } cv0, cv1;
    cv0.u[0] = w[0]; cv0.u[1] = w[1]; cv0.u[2] = w[2]; cv0.u[3] = w[3];
    cv1.u[0] = w[4]; cv1.u[1] = w[5]; cv1.u[2] = w[6]; cv1.u[3] = w[7];

    __builtin_amdgcn_s_setprio(1);
#pragma unroll
    for (int kk = 0; kk < 2; ++kk) {
      const short8 pf = kk ? cv1.s8 : cv0.s8;
#pragma unroll
      for (int m = 0; m < 4; ++m) {
        const int vr = m * 16 + lr15;
        const short8 vf = *(const short8*)(lV + vr * 64 + (((kk * 4 + lg) ^ (vr & 7)) * 8));
        oacc[m] = __builtin_amdgcn_mfma_f32_16x16x32_bf16(pf, vf, oacc[m], 0, 0, 0);
      }
      dacc = __builtin_amdgcn_mfma_f32_16x16x32_bf16(pf, onesf, dacc, 0, 0, 0);
    }
    __builtin_amdgcn_s_setprio(0);
  };

  stage(0, 0); stage(1, 64);
  asm volatile("s_waitcnt vmcnt(2)" ::: "memory");
  __builtin_amdgcn_s_barrier();
  asm volatile("" ::: "memory");
  int cur = 0;
  for (int t = 0; t < 30; ++t) {
    stage(cur == 0 ? 2 : cur - 1, (t + 2) * 64);   // buf (t+2)%3
    compute(cur);
    asm volatile("s_waitcnt vmcnt(2) lgkmcnt(0)" ::: "memory");
    __builtin_amdgcn_s_barrier();
    asm volatile("" ::: "memory");
    cur = cur == 2 ? 0 : cur + 1;
  }
  compute(cur);
  asm volatile("s_waitcnt vmcnt(0) lgkmcnt(0)" ::: "memory");
  __builtin_amdgcn_s_barrier();
  asm volatile("" ::: "memory");
  cur = cur == 2 ? 0 : cur + 1;
  compute(cur);

  const int b_ = bh >> 4, hh = bh & 15;
  f32x4 rden;
#pragma unroll
  for (int r = 0; r < 4; ++r) rden[r] = __builtin_amdgcn_rcpf(dacc[r] + 1e-6f);
#pragma unroll
  for (int n = 0; n < 4; ++n) {
    const int hd = n * 16 + lr15;
#pragma unroll
    for (int r = 0; r < 4; ++r) {
      const int tt = q0 + lg * 4 + r;
      AO[((size_t)(b_ * SEQ_T + tt) << 10) + hh * 64 + hd] = f2bf(oacc[n][r] * rden[r]);
    }
  }
}

// ------------------------------------------- output projection + residual
// 64x128 tile; 3-buffer counted-vmcnt pipeline (3 loads/thread -> vmcnt(3)).
__global__ __launch_bounds__(256) void gemm_out(
    const u16* __restrict__ A, const u16* __restrict__ W,
    const float* __restrict__ bias, const float* __restrict__ X,
    const float* __restrict__ alphap, float* __restrict__ out) {
  __shared__ u16 lds[3 * 6144];   // per buf: A 64x32 (2048) + B 128x32 (4096)
  const int col0 = blockIdx.x * 128, row0 = blockIdx.y * 64;
  const int tid = threadIdx.x, wv = tid >> 6, lane = tid & 63;
  const int lr15 = lane & 15, lg = lane >> 4;
  const int r = tid >> 2, c = tid & 3;
  const int sc = c ^ (r & 3);
  f32x4 acc[4][2];
#pragma unroll
  for (int m = 0; m < 4; ++m)
#pragma unroll
    for (int n = 0; n < 2; ++n) acc[m][n] = (f32x4){0.f, 0.f, 0.f, 0.f};

  auto stage = [&](int buf, int kt) {
    const int k0 = kt * 32;
    u16* base = lds + buf * 6144;
    gload_lds16(A + (size_t)(row0 + r) * 1024 + k0 + sc * 8, base + wv * 512);
    const u16* gB = W + (size_t)(col0 + r) * 1024 + k0 + sc * 8;
    gload_lds16(gB,             base + 2048 + wv * 512);
    gload_lds16(gB + 64 * 1024, base + 4096 + wv * 512);
  };

  auto compute = [&](int buf) {
    const u16* lA = lds + buf * 6144;
    const u16* lB = lA + 2048;
    short8 a[4], b[2];
#pragma unroll
    for (int m = 0; m < 4; ++m) {
      const int row = m * 16 + lr15;
      a[m] = *(const short8*)(lA + row * 32 + (lg ^ (row & 3)) * 8);
    }
#pragma unroll
    for (int n = 0; n < 2; ++n) {
      const int row = wv * 32 + n * 16 + lr15;
      b[n] = *(const short8*)(lB + row * 32 + (lg ^ (row & 3)) * 8);
    }
    __builtin_amdgcn_s_setprio(1);
#pragma unroll
    for (int m = 0; m < 4; ++m)
#pragma unroll
      for (int n = 0; n < 2; ++n)
        acc[m][n] = __builtin_amdgcn_mfma_f32_16x16x32_bf16(a[m], b[n], acc[m][n], 0, 0, 0);
    __builtin_amdgcn_s_setprio(0);
  };

  stage(0, 0); stage(1, 1);
  asm volatile("s_waitcnt vmcnt(3)" ::: "memory");
  __builtin_amdgcn_s_barrier();
  asm volatile("" ::: "memory");
  int cur = 0;
  for (int t = 0; t < 30; ++t) {
    stage(cur == 0 ? 2 : cur - 1, t + 2);
    compute(cur);
    __builtin_amdgcn_sched_barrier(0);
    asm volatile("s_waitcnt vmcnt(3) lgkmcnt(0)" ::: "memory");
    __builtin_amdgcn_s_barrier();
    asm volatile("" ::: "memory");
    cur = cur == 2 ? 0 : cur + 1;
  }
  compute(cur);
  __builtin_amdgcn_sched_barrier(0);
  asm volatile("s_waitcnt vmcnt(0) lgkmcnt(0)" ::: "memory");
  __builtin_amdgcn_s_barrier();
  asm volatile("" ::: "memory");
  cur = cur == 2 ? 0 : cur + 1;
  compute(cur);

  const float alpha = alphap[0];
#pragma unroll
  for (int n = 0; n < 2; ++n) {
    const int col = col0 + wv * 32 + n * 16 + lr15;
    const float bc = bias[col];
#pragma unroll
    for (int m = 0; m < 4; ++m) {
#pragma unroll
      for (int rr = 0; rr < 4; ++rr) {
        const int row = row0 + m * 16 + lg * 4 + rr;
        const size_t off = ((size_t)row << 10) + col;
        out[off] = X[off] + alpha * (acc[m][n][rr] + bc);
      }
    }
  }
}

// ------------------------------------------------------------------ launch
extern "C" void kernel_launch(void* const* d_in, const int* in_sizes, int n_in,
                              void* d_out, int out_size, void* d_ws, size_t ws_size,
                              hipStream_t stream) {
  const float* x  = (const float*)d_in[0];
  const float* wq = (const float*)d_in[1];
  const float* bq = (const float*)d_in[2];
  const float* wk = (const float*)d_in[3];
  const float* bk = (const float*)d_in[4];
  const float* wv = (const float*)d_in[5];
  const float* bv = (const float*)d_in[6];
  const float* wo = (const float*)d_in[7];
  const float* bo = (const float*)d_in[8];
  const float* alpha = (const float*)d_in[9];
  float* out = (float*)d_out;
  char* ws = (char*)d_ws;
  const size_t MB = 1u << 20;
  u16* xb  = (u16*)(ws + 0 * MB);
  u16* wqb = (u16*)(ws + 8 * MB);
  u16* wkb = (u16*)(ws + 10 * MB);
  u16* wvb = (u16*)(ws + 12 * MB);
  u16* wob = (u16*)(ws + 14 * MB);
  u16* qw  = (u16*)(ws + 16 * MB);   // [B,H,T,64] (scaled by -log2e/8)
  u16* kw  = (u16*)(ws + 24 * MB);   // [B,H,T,64]
  u16* vtw = (u16*)(ws + 32 * MB);   // [B,H,64,T]
  u16* aow = (u16*)(ws + 40 * MB);   // [4096,1024]

  cvt_all<<<8192, 256, 0, stream>>>(x, wq, wk, wv, wo, xb, wqb, wkb, wvb, wob);
  gemm_qkv<<<dim3(24, 32), 512, 0, stream>>>(xb, wqb, wkb, wvb, bq, bk, bv, qw, kw, vtw);
  attn_sig<<<dim3(16, 32), 512, 0, stream>>>(qw, kw, vtw, aow);
  gemm_out<<<dim3(8, 64), 256, 0, stream>>>(aow, wob, bo, x, alpha, out);
}

// Round 6
// 198.200 us; speedup vs baseline: 1.0898x; 1.0013x over previous
//
#include <hip/hip_runtime.h>

#define SEQ_T 2048
#define NHEAD 16

typedef unsigned short u16;
typedef __attribute__((ext_vector_type(2))) float f32x2;
typedef __attribute__((ext_vector_type(4))) float f32x4;
typedef __attribute__((ext_vector_type(8))) short short8;
typedef __attribute__((ext_vector_type(4))) unsigned short u16x4;

__device__ __forceinline__ u16 f2bf(float f) {
  unsigned u = __float_as_uint(f);
  unsigned r = (u + 0x7FFFu + ((u >> 16) & 1u)) >> 16;
  return (u16)r;
}

__device__ __forceinline__ void gload_lds16(const void* g, void* l) {
  __builtin_amdgcn_global_load_lds((const __attribute__((address_space(1))) void*)g,
                                   (__attribute__((address_space(3))) void*)l, 16, 0, 0);
}

// packed sigmoid pair: g = 1/(1+2^s) for two scores, result = packed bf16.
// exp2 (trans) + pk_add + 2x magic-sub + pk_fma(neg) + pk_mul + cvt_pk.
__device__ __forceinline__ unsigned sig2pk(float s0, float s1, f32x2 one2, f32x2 two2) {
  f32x2 e;
  e[0] = __builtin_amdgcn_exp2f(s0);
  e[1] = __builtin_amdgcn_exp2f(s1);
  f32x2 d;
  asm("v_pk_add_f32 %0, %1, %2" : "=v"(d) : "v"(e), "v"(one2));
  f32x2 y;
  y[0] = __uint_as_float(0x7EF311C3u - __float_as_uint(d[0]));
  y[1] = __uint_as_float(0x7EF311C3u - __float_as_uint(d[1]));
  f32x2 w;
  asm("v_pk_fma_f32 %0, %1, %2, %3 neg_lo:[1,0,0] neg_hi:[1,0,0]"
      : "=v"(w) : "v"(d), "v"(y), "v"(two2));            // w = 2 - d*y
  f32x2 g;
  asm("v_pk_mul_f32 %0, %1, %2" : "=v"(g) : "v"(y), "v"(w));   // g = y*(2-dy)
  unsigned r;
  asm("v_cvt_pk_bf16_f32 %0, %1, %2" : "=v"(r) : "v"(g[0]), "v"(g[1]));
  return r;
}

// ---------------------------------------------------------------- convert
__global__ __launch_bounds__(256) void cvt_all(
    const float* __restrict__ x, const float* __restrict__ wq, const float* __restrict__ wk,
    const float* __restrict__ wv, const float* __restrict__ wo,
    u16* __restrict__ xb, u16* __restrict__ wqb, u16* __restrict__ wkb,
    u16* __restrict__ wvb, u16* __restrict__ wob) {
  const int bid = blockIdx.x;
  const float* s; u16* d; int base;
  if (bid < 4096) { s = x; d = xb; base = bid; }
  else {
    const int w = (bid - 4096) >> 10;
    base = (bid - 4096) & 1023;
    if (w == 0)      { s = wq; d = wqb; }
    else if (w == 1) { s = wk; d = wkb; }
    else if (w == 2) { s = wv; d = wvb; }
    else             { s = wo; d = wob; }
  }
  const int i = base * 256 + threadIdx.x;
  const float4 v = ((const float4*)s)[i];
  u16x4 o;
  o[0] = f2bf(v.x); o[1] = f2bf(v.y); o[2] = f2bf(v.z); o[3] = f2bf(v.w);
  ((u16x4*)d)[i] = o;
}

// ----------------------------------------- 4-wave m97-shape GEMM core (128x128)
// 256 thr = 4 waves 2x2, each 64x64 (16 MFMA : 8 ds_read per K-step).
// 3-buf counted-vmcnt: stage(t+2) -> compute(t) -> vmcnt(4) -> barrier.
static __device__ __forceinline__ void gemm_core4(
    const u16* __restrict__ A, const u16* __restrict__ Bmat,
    u16* lds, int row0, int col0, int tid, f32x4 acc[4][4]) {
  const int wv = tid >> 6, lane = tid & 63;
  const int wr = wv >> 1, wc = wv & 1;
  const int lr15 = lane & 15, lg = lane >> 4;
  const int r = tid >> 2, c = tid & 3;
  const int sc = c ^ (r & 3);

  auto stage = [&](const int buf, int kt) {
    const int k0 = kt * 32;
    u16* base = lds + buf * 8192;
#pragma unroll
    for (int v = 0; v < 2; ++v) {
      gload_lds16(A    + (size_t)(row0 + v * 64 + r) * 1024 + k0 + sc * 8,
                  base + v * 2048 + wv * 512);
      gload_lds16(Bmat + (size_t)(col0 + v * 64 + r) * 1024 + k0 + sc * 8,
                  base + 4096 + v * 2048 + wv * 512);
    }
  };

  auto compute = [&](const int buf) {
    const u16* lA = lds + buf * 8192;
    const u16* lB = lA + 4096;
    short8 a[4], b[4];
#pragma unroll
    for (int m = 0; m < 4; ++m) {
      const int row = wr * 64 + m * 16 + lr15;
      a[m] = *(const short8*)(lA + row * 32 + (lg ^ (row & 3)) * 8);
    }
#pragma unroll
    for (int n = 0; n < 4; ++n) {
      const int row = wc * 64 + n * 16 + lr15;
      b[n] = *(const short8*)(lB + row * 32 + (lg ^ (row & 3)) * 8);
    }
    __builtin_amdgcn_s_setprio(1);
#pragma unroll
    for (int m = 0; m < 4; ++m)
#pragma unroll
      for (int n = 0; n < 4; ++n)
        acc[m][n] = __builtin_amdgcn_mfma_f32_16x16x32_bf16(a[m], b[n], acc[m][n], 0, 0, 0);
    __builtin_amdgcn_s_setprio(0);
  };

  stage(0, 0); stage(1, 1);
  asm volatile("s_waitcnt vmcnt(4)" ::: "memory");
  __builtin_amdgcn_s_barrier();
  asm volatile("" ::: "memory");
#pragma unroll 1
  for (int t = 0; t < 30; t += 3) {
#pragma unroll
    for (int j = 0; j < 3; ++j) {                     // static buf ids
      const int sb = (j + 2) % 3;
      stage(sb, t + j + 2);
      compute(j);
      __builtin_amdgcn_sched_barrier(0);
      asm volatile("s_waitcnt vmcnt(4) lgkmcnt(0)" ::: "memory");
      __builtin_amdgcn_s_barrier();
      asm volatile("" ::: "memory");
    }
  }
  compute(0);                                          // tile 30
  __builtin_amdgcn_sched_barrier(0);
  asm volatile("s_waitcnt vmcnt(0) lgkmcnt(0)" ::: "memory");
  __builtin_amdgcn_s_barrier();
  asm volatile("" ::: "memory");
  compute(1);                                          // tile 31
}

// ---------------------------------------------------- fused QKV projection
// Q is additionally scaled by -0.125*log2(e) so attn sigmoid = rcp(1+exp2(s)).
__global__ __launch_bounds__(256, 3) void gemm_qkv(
    const u16* __restrict__ X,
    const u16* __restrict__ WQ, const u16* __restrict__ WK, const u16* __restrict__ WV,
    const float* __restrict__ BQ, const float* __restrict__ BK, const float* __restrict__ BV,
    u16* __restrict__ OQ, u16* __restrict__ OK, u16* __restrict__ OV) {
  __shared__ u16 lds[3 * 8192];
  const int which = blockIdx.x >> 3;
  const int col0 = (blockIdx.x & 7) * 128;
  const int row0 = blockIdx.y * 128;
  const u16* W = (which == 0) ? WQ : ((which == 1) ? WK : WV);
  const float* bias = (which == 0) ? BQ : ((which == 1) ? BK : BV);
  u16* out = (which == 0) ? OQ : ((which == 1) ? OK : OV);
  const int tid = threadIdx.x;
  f32x4 acc[4][4];
#pragma unroll
  for (int m = 0; m < 4; ++m)
#pragma unroll
    for (int n = 0; n < 4; ++n) acc[m][n] = (f32x4){0.f, 0.f, 0.f, 0.f};

  gemm_core4(X, W, lds, row0, col0, tid, acc);

  const float qscale = (which == 0) ? -0.18033688011112042f : 1.0f;
  const int wv = tid >> 6, lane = tid & 63;
  const int wr = wv >> 1, wc = wv & 1;
#pragma unroll
  for (int n = 0; n < 4; ++n) {
    const int col = col0 + wc * 64 + n * 16 + (lane & 15);
    const float bc = bias[col];
    const int hh = col >> 6, hd = col & 63;
#pragma unroll
    for (int m = 0; m < 4; ++m) {
#pragma unroll
      for (int r = 0; r < 4; ++r) {
        const int row = row0 + wr * 64 + m * 16 + (lane >> 4) * 4 + r;
        const int b_ = row >> 11, tt = row & 2047;
        const u16 h = f2bf((acc[m][n][r] + bc) * qscale);
        if (which != 2) {
          out[(((size_t)(b_ * NHEAD + hh) * SEQ_T + tt) << 6) + hd] = h;
        } else {
          out[(((size_t)(b_ * NHEAD + hh) << 6) + hd) * SEQ_T + tt] = h;
        }
      }
    }
  }
}

// ------------------------------------------------------ sigmoid attention
// grid (16, 32): 8 waves x 16 q-rows; 512 blocks = 2/CU (4 w/SIMD).
// Swapped QK^T with sigma-permuted K rows; packed-f32 sigmoid packs in-register
// into the PV A-fragment. 3-buf counted-vmcnt, x3 static-unrolled rotation.
__device__ __forceinline__ int sigp(int u) {
  return (u & 35) | ((u & 8) << 1) | ((u & 4) << 1) | ((u & 16) >> 2);
}

__global__ __launch_bounds__(512, 4) void attn_sig(
    const u16* __restrict__ Q, const u16* __restrict__ K,
    const u16* __restrict__ Vt, u16* __restrict__ AO) {
  __shared__ u16 lds[3 * 8192];   // per buf: K[64 s(perm)][64 hd] 8KB, V[64 hd][64 s] 8KB
  const int tid = threadIdx.x, wv = tid >> 6, lane = tid & 63;
  const int lr15 = lane & 15, lg = lane >> 4;
  const int bh = blockIdx.y;
  const int q0 = blockIdx.x * 128 + wv * 16;
  const u16* Qb = Q  + (size_t)bh * SEQ_T * 64;
  const u16* Kb = K  + (size_t)bh * SEQ_T * 64;
  const u16* Vb = Vt + (size_t)bh * 64 * SEQ_T;

  short8 qf[2];
#pragma unroll
  for (int kk = 0; kk < 2; ++kk)
    qf[kk] = *(const short8*)(Qb + (size_t)(q0 + lr15) * 64 + kk * 32 + lg * 8);
  asm volatile("s_waitcnt vmcnt(0)" ::: "memory");   // clean vm counter

  short8 onesf;
#pragma unroll
  for (int i = 0; i < 8; ++i) onesf[i] = (short)0x3F80;
  const f32x4 zac = (f32x4){0.f, 0.f, 0.f, 0.f};     // const zero C operand
  const f32x2 one2 = (f32x2){1.f, 1.f};
  const f32x2 two2 = (f32x2){2.f, 2.f};

  f32x4 oacc[4];
#pragma unroll
  for (int n = 0; n < 4; ++n) oacc[n] = (f32x4){0.f, 0.f, 0.f, 0.f};
  f32x4 dacc = (f32x4){0.f, 0.f, 0.f, 0.f};

  const int r0 = tid >> 3, c0 = tid & 7;    // 512 threads cover 64 rows x 8 chunks
  const int sc0 = c0 ^ (r0 & 7);
  const int sg0 = sigp(r0);

  auto stage = [&](const int buf, int s0) {
    gload_lds16(Kb + (size_t)(s0 + sg0) * 64 + sc0 * 8,  lds + buf * 8192 + wv * 512);
    gload_lds16(Vb + (size_t)r0 * SEQ_T + s0 + sc0 * 8,  lds + buf * 8192 + 4096 + wv * 512);
  };

  auto compute = [&](const int buf) {
    const u16* lK = lds + buf * 8192;
    const u16* lV = lK + 4096;
    f32x4 sacc[4];
    __builtin_amdgcn_s_setprio(1);
#pragma unroll
    for (int n = 0; n < 4; ++n) {            // kk=0 with const-zero C
      const int row = n * 16 + lr15;
      const short8 kf = *(const short8*)(lK + row * 64 + ((lg ^ (row & 7)) * 8));
      sacc[n] = __builtin_amdgcn_mfma_f32_16x16x32_bf16(kf, qf[0], zac, 0, 0, 0);
    }
#pragma unroll
    for (int n = 0; n < 4; ++n) {            // kk=1 accumulate
      const int row = n * 16 + lr15;
      const short8 kf = *(const short8*)(lK + row * 64 + (((4 + lg) ^ (row & 7)) * 8));
      sacc[n] = __builtin_amdgcn_mfma_f32_16x16x32_bf16(kf, qf[1], sacc[n], 0, 0, 0);
    }
    __builtin_amdgcn_s_setprio(0);

    unsigned w[8];
#pragma unroll
    for (int n = 0; n < 4; ++n) {
      w[n * 2 + 0] = sig2pk(sacc[n][0], sacc[n][1], one2, two2);
      w[n * 2 + 1] = sig2pk(sacc[n][2], sacc[n][3], one2, two2);
    }
    union { unsigned u[4]; short8 s8; } cv0, cv1;
    cv0.u[0] = w[0]; cv0.u[1] = w[1]; cv0.u[2] = w[2]; cv0.u[3] = w[3];
    cv1.u[0] = w[4]; cv1.u[1] = w[5]; cv1.u[2] = w[6]; cv1.u[3] = w[7];

    __builtin_amdgcn_s_setprio(1);
#pragma unroll
    for (int kk = 0; kk < 2; ++kk) {
      const short8 pf = kk ? cv1.s8 : cv0.s8;
#pragma unroll
      for (int m = 0; m < 4; ++m) {
        const int vr = m * 16 + lr15;
        const short8 vf = *(const short8*)(lV + vr * 64 + (((kk * 4 + lg) ^ (vr & 7)) * 8));
        oacc[m] = __builtin_amdgcn_mfma_f32_16x16x32_bf16(pf, vf, oacc[m], 0, 0, 0);
      }
      dacc = __builtin_amdgcn_mfma_f32_16x16x32_bf16(pf, onesf, dacc, 0, 0, 0);
    }
    __builtin_amdgcn_s_setprio(0);
  };

  stage(0, 0); stage(1, 64);
  asm volatile("s_waitcnt vmcnt(2)" ::: "memory");
  __builtin_amdgcn_s_barrier();
  asm volatile("" ::: "memory");
#pragma unroll 1
  for (int t = 0; t < 30; t += 3) {
#pragma unroll
    for (int j = 0; j < 3; ++j) {            // static buf ids: compute j, stage (j+2)%3
      stage((j + 2) % 3, (t + j + 2) * 64);
      compute(j);
      asm volatile("s_waitcnt vmcnt(2) lgkmcnt(0)" ::: "memory");
      __builtin_amdgcn_s_barrier();
      asm volatile("" ::: "memory");
    }
  }
  compute(0);                                 // tile 30
  asm volatile("s_waitcnt vmcnt(0) lgkmcnt(0)" ::: "memory");
  __builtin_amdgcn_s_barrier();
  asm volatile("" ::: "memory");
  compute(1);                                 // tile 31

  const int b_ = bh >> 4, hh = bh & 15;
  f32x4 rden;
#pragma unroll
  for (int r = 0; r < 4; ++r) rden[r] = __builtin_amdgcn_rcpf(dacc[r] + 1e-6f);
#pragma unroll
  for (int n = 0; n < 4; ++n) {
    const int hd = n * 16 + lr15;
#pragma unroll
    for (int r = 0; r < 4; ++r) {
      const int tt = q0 + lg * 4 + r;
      AO[((size_t)(b_ * SEQ_T + tt) << 10) + hh * 64 + hd] = f2bf(oacc[n][r] * rden[r]);
    }
  }
}

// ------------------------------------------- output projection + residual
// 64x128 tile, BK=64 (16 MFMA/wave/step), 3-buf counted vmcnt(6), 2 blocks/CU.
__global__ __launch_bounds__(256) void gemm_out(
    const u16* __restrict__ A, const u16* __restrict__ W,
    const float* __restrict__ bias, const float* __restrict__ X,
    const float* __restrict__ alphap, float* __restrict__ out) {
  __shared__ u16 lds[3 * 12288];   // per buf: A 64x64 (8KB) + B 128x64 (16KB)
  const int col0 = blockIdx.x * 128, row0 = blockIdx.y * 64;
  const int tid = threadIdx.x, wv = tid >> 6, lane = tid & 63;
  const int lr15 = lane & 15, lg = lane >> 4;
  const int rA = tid >> 3, cA = tid & 7;
  const int scA = cA ^ (rA & 7);
  f32x4 acc[4][2];
#pragma unroll
  for (int m = 0; m < 4; ++m)
#pragma unroll
    for (int n = 0; n < 2; ++n) acc[m][n] = (f32x4){0.f, 0.f, 0.f, 0.f};

  auto stage = [&](int buf, int kt) {
    const int k0 = kt * 64;
    u16* base = lds + buf * 12288;
#pragma unroll
    for (int v = 0; v < 2; ++v)
      gload_lds16(A + (size_t)(row0 + v * 32 + rA) * 1024 + k0 + scA * 8,
                  base + v * 2048 + wv * 512);
#pragma unroll
    for (int v = 0; v < 4; ++v)
      gload_lds16(W + (size_t)(col0 + v * 32 + rA) * 1024 + k0 + scA * 8,
                  base + 4096 + v * 2048 + wv * 512);
  };

  auto compute = [&](int buf) {
    const u16* lA = lds + buf * 12288;
    const u16* lB = lA + 4096;
#pragma unroll
    for (int kk = 0; kk < 2; ++kk) {
      short8 a[4], b[2];
#pragma unroll
      for (int m = 0; m < 4; ++m) {
        const int row = m * 16 + lr15;
        a[m] = *(const short8*)(lA + row * 64 + (((kk * 4 + lg) ^ (row & 7)) * 8));
      }
#pragma unroll
      for (int n = 0; n < 2; ++n) {
        const int row = wv * 32 + n * 16 + lr15;
        b[n] = *(const short8*)(lB + row * 64 + (((kk * 4 + lg) ^ (row & 7)) * 8));
      }
      __builtin_amdgcn_s_setprio(1);
#pragma unroll
      for (int m = 0; m < 4; ++m)
#pragma unroll
        for (int n = 0; n < 2; ++n)
          acc[m][n] = __builtin_amdgcn_mfma_f32_16x16x32_bf16(a[m], b[n], acc[m][n], 0, 0, 0);
      __builtin_amdgcn_s_setprio(0);
    }
  };

  stage(0, 0); stage(1, 1);
  asm volatile("s_waitcnt vmcnt(6)" ::: "memory");
  __builtin_amdgcn_s_barrier();
  asm volatile("" ::: "memory");
  int cur = 0;
  for (int t = 0; t < 14; ++t) {
    stage(cur == 0 ? 2 : cur - 1, t + 2);
    compute(cur);
    __builtin_amdgcn_sched_barrier(0);
    asm volatile("s_waitcnt vmcnt(6) lgkmcnt(0)" ::: "memory");
    __builtin_amdgcn_s_barrier();
    asm volatile("" ::: "memory");
    cur = cur == 2 ? 0 : cur + 1;
  }
  compute(cur);                               // tile 14
  __builtin_amdgcn_sched_barrier(0);
  asm volatile("s_waitcnt vmcnt(0) lgkmcnt(0)" ::: "memory");
  __builtin_amdgcn_s_barrier();
  asm volatile("" ::: "memory");
  cur = cur == 2 ? 0 : cur + 1;
  compute(cur);                               // tile 15

  const float alpha = alphap[0];
#pragma unroll
  for (int n = 0; n < 2; ++n) {
    const int col = col0 + wv * 32 + n * 16 + lr15;
    const float bc = bias[col];
#pragma unroll
    for (int m = 0; m < 4; ++m) {
#pragma unroll
      for (int rr = 0; rr < 4; ++rr) {
        const int row = row0 + m * 16 + lg * 4 + rr;
        const size_t off = ((size_t)row << 10) + col;
        out[off] = X[off] + alpha * (acc[m][n][rr] + bc);
      }
    }
  }
}

// ------------------------------------------------------------------ launch
extern "C" void kernel_launch(void* const* d_in, const int* in_sizes, int n_in,
                              void* d_out, int out_size, void* d_ws, size_t ws_size,
                              hipStream_t stream) {
  const float* x  = (const float*)d_in[0];
  const float* wq = (const float*)d_in[1];
  const float* bq = (const float*)d_in[2];
  const float* wk = (const float*)d_in[3];
  const float* bk = (const float*)d_in[4];
  const float* wv = (const float*)d_in[5];
  const float* bv = (const float*)d_in[6];
  const float* wo = (const float*)d_in[7];
  const float* bo = (const float*)d_in[8];
  const float* alpha = (const float*)d_in[9];
  float* out = (float*)d_out;
  char* ws = (char*)d_ws;
  const size_t MB = 1u << 20;
  u16* xb  = (u16*)(ws + 0 * MB);
  u16* wqb = (u16*)(ws + 8 * MB);
  u16* wkb = (u16*)(ws + 10 * MB);
  u16* wvb = (u16*)(ws + 12 * MB);
  u16* wob = (u16*)(ws + 14 * MB);
  u16* qw  = (u16*)(ws + 16 * MB);   // [B,H,T,64] (scaled by -log2e/8)
  u16* kw  = (u16*)(ws + 24 * MB);   // [B,H,T,64]
  u16* vtw = (u16*)(ws + 32 * MB);   // [B,H,64,T]
  u16* aow = (u16*)(ws + 40 * MB);   // [4096,1024]

  cvt_all<<<8192, 256, 0, stream>>>(x, wq, wk, wv, wo, xb, wqb, wkb, wvb, wob);
  gemm_qkv<<<dim3(24, 32), 256, 0, stream>>>(xb, wqb, wkb, wvb, bq, bk, bv, qw, kw, vtw);
  attn_sig<<<dim3(16, 32), 512, 0, stream>>>(qw, kw, vtw, aow);
  gemm_out<<<dim3(8, 64), 256, 0, stream>>>(aow, wob, bo, x, alpha, out);
}

// Round 7
// 194.106 us; speedup vs baseline: 1.1127x; 1.0211x over previous
//
#include <hip/hip_runtime.h>

#define SEQ_T 2048
#define NHEAD 16

typedef unsigned short u16;
typedef __attribute__((ext_vector_type(2))) float f32x2;
typedef __attribute__((ext_vector_type(4))) float f32x4;
typedef __attribute__((ext_vector_type(8))) short short8;
typedef __attribute__((ext_vector_type(4))) unsigned short u16x4;

__device__ __forceinline__ u16 f2bf(float f) {
  unsigned u = __float_as_uint(f);
  unsigned r = (u + 0x7FFFu + ((u >> 16) & 1u)) >> 16;
  return (u16)r;
}

__device__ __forceinline__ void gload_lds16(const void* g, void* l) {
  __builtin_amdgcn_global_load_lds((const __attribute__((address_space(1))) void*)g,
                                   (__attribute__((address_space(3))) void*)l, 16, 0, 0);
}

// packed sigmoid pair: g = 1/(1+2^s) for two scores, result = packed bf16.
__device__ __forceinline__ unsigned sig2pk(float s0, float s1, f32x2 one2, f32x2 two2) {
  f32x2 e;
  e[0] = __builtin_amdgcn_exp2f(s0);
  e[1] = __builtin_amdgcn_exp2f(s1);
  f32x2 d;
  asm("v_pk_add_f32 %0, %1, %2" : "=v"(d) : "v"(e), "v"(one2));
  f32x2 y;
  y[0] = __uint_as_float(0x7EF311C3u - __float_as_uint(d[0]));
  y[1] = __uint_as_float(0x7EF311C3u - __float_as_uint(d[1]));
  f32x2 w;
  asm("v_pk_fma_f32 %0, %1, %2, %3 neg_lo:[1,0,0] neg_hi:[1,0,0]"
      : "=v"(w) : "v"(d), "v"(y), "v"(two2));            // w = 2 - d*y
  f32x2 g;
  asm("v_pk_mul_f32 %0, %1, %2" : "=v"(g) : "v"(y), "v"(w));   // g = y*(2-dy)
  unsigned r;
  asm("v_cvt_pk_bf16_f32 %0, %1, %2" : "=v"(r) : "v"(g[0]), "v"(g[1]));
  return r;
}

// ---------------------------------------------------------------- convert
__global__ __launch_bounds__(256) void cvt_all(
    const float* __restrict__ x, const float* __restrict__ wq, const float* __restrict__ wk,
    const float* __restrict__ wv, const float* __restrict__ wo,
    u16* __restrict__ xb, u16* __restrict__ wqb, u16* __restrict__ wkb,
    u16* __restrict__ wvb, u16* __restrict__ wob) {
  const int bid = blockIdx.x;
  const float* s; u16* d; int base;
  if (bid < 4096) { s = x; d = xb; base = bid; }
  else {
    const int w = (bid - 4096) >> 10;
    base = (bid - 4096) & 1023;
    if (w == 0)      { s = wq; d = wqb; }
    else if (w == 1) { s = wk; d = wkb; }
    else if (w == 2) { s = wv; d = wvb; }
    else             { s = wo; d = wob; }
  }
  const int i = base * 256 + threadIdx.x;
  const float4 v = ((const float4*)s)[i];
  u16x4 o;
  o[0] = f2bf(v.x); o[1] = f2bf(v.y); o[2] = f2bf(v.z); o[3] = f2bf(v.w);
  ((u16x4*)d)[i] = o;
}

// ----------------------------------------- 4-wave m97-shape GEMM core (128x128)
static __device__ __forceinline__ void gemm_core4(
    const u16* __restrict__ A, const u16* __restrict__ Bmat,
    u16* lds, int row0, int col0, int tid, f32x4 acc[4][4]) {
  const int wv = tid >> 6, lane = tid & 63;
  const int wr = wv >> 1, wc = wv & 1;
  const int lr15 = lane & 15, lg = lane >> 4;
  const int r = tid >> 2, c = tid & 3;
  const int sc = c ^ (r & 3);

  auto stage = [&](const int buf, int kt) {
    const int k0 = kt * 32;
    u16* base = lds + buf * 8192;
#pragma unroll
    for (int v = 0; v < 2; ++v) {
      gload_lds16(A    + (size_t)(row0 + v * 64 + r) * 1024 + k0 + sc * 8,
                  base + v * 2048 + wv * 512);
      gload_lds16(Bmat + (size_t)(col0 + v * 64 + r) * 1024 + k0 + sc * 8,
                  base + 4096 + v * 2048 + wv * 512);
    }
  };

  auto compute = [&](const int buf) {
    const u16* lA = lds + buf * 8192;
    const u16* lB = lA + 4096;
    short8 a[4], b[4];
#pragma unroll
    for (int m = 0; m < 4; ++m) {
      const int row = wr * 64 + m * 16 + lr15;
      a[m] = *(const short8*)(lA + row * 32 + (lg ^ (row & 3)) * 8);
    }
#pragma unroll
    for (int n = 0; n < 4; ++n) {
      const int row = wc * 64 + n * 16 + lr15;
      b[n] = *(const short8*)(lB + row * 32 + (lg ^ (row & 3)) * 8);
    }
    __builtin_amdgcn_s_setprio(1);
#pragma unroll
    for (int m = 0; m < 4; ++m)
#pragma unroll
      for (int n = 0; n < 4; ++n)
        acc[m][n] = __builtin_amdgcn_mfma_f32_16x16x32_bf16(a[m], b[n], acc[m][n], 0, 0, 0);
    __builtin_amdgcn_s_setprio(0);
  };

  stage(0, 0); stage(1, 1);
  asm volatile("s_waitcnt vmcnt(4)" ::: "memory");
  __builtin_amdgcn_s_barrier();
  asm volatile("" ::: "memory");
#pragma unroll 1
  for (int t = 0; t < 30; t += 3) {
#pragma unroll
    for (int j = 0; j < 3; ++j) {                     // static buf ids
      const int sb = (j + 2) % 3;
      stage(sb, t + j + 2);
      compute(j);
      __builtin_amdgcn_sched_barrier(0);
      asm volatile("s_waitcnt vmcnt(4) lgkmcnt(0)" ::: "memory");
      __builtin_amdgcn_s_barrier();
      asm volatile("" ::: "memory");
    }
  }
  compute(0);                                          // tile 30
  __builtin_amdgcn_sched_barrier(0);
  asm volatile("s_waitcnt vmcnt(0) lgkmcnt(0)" ::: "memory");
  __builtin_amdgcn_s_barrier();
  asm volatile("" ::: "memory");
  compute(1);                                          // tile 31
}

// ---------------------------------------------------- fused QKV projection
// Q is additionally scaled by -0.125*log2(e) so attn sigmoid = rcp(1+exp2(s)).
// Epilogue: stage C-tile in LDS ([t][col] for Q/K, [col][t] for V) then emit
// fully-coalesced 16B/lane stores — the old V path was a 2B x 4KB-stride scatter.
__global__ __launch_bounds__(256, 3) void gemm_qkv(
    const u16* __restrict__ X,
    const u16* __restrict__ WQ, const u16* __restrict__ WK, const u16* __restrict__ WV,
    const float* __restrict__ BQ, const float* __restrict__ BK, const float* __restrict__ BV,
    u16* __restrict__ OQ, u16* __restrict__ OK, u16* __restrict__ OV) {
  __shared__ u16 lds[3 * 8192];
  const int which = blockIdx.x >> 3;
  const int col0 = (blockIdx.x & 7) * 128;
  const int row0 = blockIdx.y * 128;
  const u16* W = (which == 0) ? WQ : ((which == 1) ? WK : WV);
  const float* bias = (which == 0) ? BQ : ((which == 1) ? BK : BV);
  u16* out = (which == 0) ? OQ : ((which == 1) ? OK : OV);
  const int tid = threadIdx.x;
  f32x4 acc[4][4];
#pragma unroll
  for (int m = 0; m < 4; ++m)
#pragma unroll
    for (int n = 0; n < 4; ++n) acc[m][n] = (f32x4){0.f, 0.f, 0.f, 0.f};

  gemm_core4(X, W, lds, row0, col0, tid, acc);

  // ---- epilogue: regs -> LDS (layout per output) -> coalesced stores
  __syncthreads();                       // all waves done reading staging LDS
  const float qscale = (which == 0) ? -0.18033688011112042f : 1.0f;
  const int wv = tid >> 6, lane = tid & 63;
  const int wr = wv >> 1, wc = wv & 1;
  const int lr15 = lane & 15, lg = lane >> 4;
  u16* ldsC = lds;                       // 128x128 u16 = 32KB (fits in 48KB)
#pragma unroll
  for (int n = 0; n < 4; ++n) {
    const int cloc = wc * 64 + n * 16 + lr15;
    const float bc = bias[col0 + cloc];
#pragma unroll
    for (int m = 0; m < 4; ++m) {
#pragma unroll
      for (int r = 0; r < 4; ++r) {
        const int rloc = wr * 64 + m * 16 + lg * 4 + r;
        const u16 h = f2bf((acc[m][n][r] + bc) * qscale);
        if (which != 2) ldsC[rloc * 128 + cloc] = h;   // [t][col]
        else            ldsC[cloc * 128 + rloc] = h;   // [col][t]
      }
    }
  }
  __syncthreads();

  const int b_ = row0 >> 11;             // batch
  const int row_t = row0 & 2047;         // t within batch
  const int hh0 = col0 >> 6;             // first head of this col tile
  const int h = wv >> 1;                 // wave -> head (0/1)
  if (which != 2) {
    // Q/K: [B,H,T,64]; wave covers head h, t-half (wv&1)*64; 1KB/store-instr
    const int t0 = (wv & 1) * 64 + (lane >> 3);
    const int chunk = lane & 7;
    u16* gb = out + ((size_t)(b_ * NHEAD + hh0 + h) * SEQ_T + row_t) * 64 + chunk * 8;
#pragma unroll
    for (int j = 0; j < 8; ++j) {
      const int t = t0 + j * 8;
      *(short8*)(gb + (size_t)t * 64) = *(const short8*)(ldsC + t * 128 + h * 64 + chunk * 8);
    }
  } else {
    // V: [B,H,64,T]; wave covers head h, t-tile (wv&1); 128B segments per lane
    const int tt = wv & 1;
    const int tchunk = lane & 7;
    const int hd0 = lane >> 3;
    u16* gb = out + ((size_t)(b_ * NHEAD + hh0 + h) * 64) * SEQ_T
                  + row_t + tt * 64 + tchunk * 8;
#pragma unroll
    for (int j = 0; j < 8; ++j) {
      const int hd = hd0 + j * 8;
      *(short8*)(gb + (size_t)hd * SEQ_T) =
          *(const short8*)(ldsC + (h * 64 + hd) * 128 + tt * 64 + tchunk * 8);
    }
  }
}

// ------------------------------------------------------ sigmoid attention
// grid (16, 32): 8 waves x 16 q-rows; 512 blocks = 2/CU (4 w/SIMD).
__device__ __forceinline__ int sigp(int u) {
  return (u & 35) | ((u & 8) << 1) | ((u & 4) << 1) | ((u & 16) >> 2);
}

__global__ __launch_bounds__(512, 4) void attn_sig(
    const u16* __restrict__ Q, const u16* __restrict__ K,
    const u16* __restrict__ Vt, u16* __restrict__ AO) {
  __shared__ u16 lds[3 * 8192];   // per buf: K[64 s(perm)][64 hd] 8KB, V[64 hd][64 s] 8KB
  const int tid = threadIdx.x, wv = tid >> 6, lane = tid & 63;
  const int lr15 = lane & 15, lg = lane >> 4;
  const int bh = blockIdx.y;
  const int q0 = blockIdx.x * 128 + wv * 16;
  const u16* Qb = Q  + (size_t)bh * SEQ_T * 64;
  const u16* Kb = K  + (size_t)bh * SEQ_T * 64;
  const u16* Vb = Vt + (size_t)bh * 64 * SEQ_T;

  short8 qf[2];
#pragma unroll
  for (int kk = 0; kk < 2; ++kk)
    qf[kk] = *(const short8*)(Qb + (size_t)(q0 + lr15) * 64 + kk * 32 + lg * 8);
  asm volatile("s_waitcnt vmcnt(0)" ::: "memory");   // clean vm counter

  short8 onesf;
#pragma unroll
  for (int i = 0; i < 8; ++i) onesf[i] = (short)0x3F80;
  const f32x4 zac = (f32x4){0.f, 0.f, 0.f, 0.f};     // const zero C operand
  const f32x2 one2 = (f32x2){1.f, 1.f};
  const f32x2 two2 = (f32x2){2.f, 2.f};

  f32x4 oacc[4];
#pragma unroll
  for (int n = 0; n < 4; ++n) oacc[n] = (f32x4){0.f, 0.f, 0.f, 0.f};
  f32x4 dacc = (f32x4){0.f, 0.f, 0.f, 0.f};

  const int r0 = tid >> 3, c0 = tid & 7;    // 512 threads cover 64 rows x 8 chunks
  const int sc0 = c0 ^ (r0 & 7);
  const int sg0 = sigp(r0);

  auto stage = [&](const int buf, int s0) {
    gload_lds16(Kb + (size_t)(s0 + sg0) * 64 + sc0 * 8,  lds + buf * 8192 + wv * 512);
    gload_lds16(Vb + (size_t)r0 * SEQ_T + s0 + sc0 * 8,  lds + buf * 8192 + 4096 + wv * 512);
  };

  auto compute = [&](const int buf) {
    const u16* lK = lds + buf * 8192;
    const u16* lV = lK + 4096;
    f32x4 sacc[4];
    __builtin_amdgcn_s_setprio(1);
#pragma unroll
    for (int n = 0; n < 4; ++n) {            // kk=0 with const-zero C
      const int row = n * 16 + lr15;
      const short8 kf = *(const short8*)(lK + row * 64 + ((lg ^ (row & 7)) * 8));
      sacc[n] = __builtin_amdgcn_mfma_f32_16x16x32_bf16(kf, qf[0], zac, 0, 0, 0);
    }
#pragma unroll
    for (int n = 0; n < 4; ++n) {            // kk=1 accumulate
      const int row = n * 16 + lr15;
      const short8 kf = *(const short8*)(lK + row * 64 + (((4 + lg) ^ (row & 7)) * 8));
      sacc[n] = __builtin_amdgcn_mfma_f32_16x16x32_bf16(kf, qf[1], sacc[n], 0, 0, 0);
    }
    __builtin_amdgcn_s_setprio(0);

    unsigned w[8];
#pragma unroll
    for (int n = 0; n < 4; ++n) {
      w[n * 2 + 0] = sig2pk(sacc[n][0], sacc[n][1], one2, two2);
      w[n * 2 + 1] = sig2pk(sacc[n][2], sacc[n][3], one2, two2);
    }
    union { unsigned u[4]; short8 s8; } cv0, cv1;
    cv0.u[0] = w[0]; cv0.u[1] = w[1]; cv0.u[2] = w[2]; cv0.u[3] = w[3];
    cv1.u[0] = w[4]; cv1.u[1] = w[5]; cv1.u[2] = w[6]; cv1.u[3] = w[7];

    __builtin_amdgcn_s_setprio(1);
#pragma unroll
    for (int kk = 0; kk < 2; ++kk) {
      const short8 pf = kk ? cv1.s8 : cv0.s8;
#pragma unroll
      for (int m = 0; m < 4; ++m) {
        const int vr = m * 16 + lr15;
        const short8 vf = *(const short8*)(lV + vr * 64 + (((kk * 4 + lg) ^ (vr & 7)) * 8));
        oacc[m] = __builtin_amdgcn_mfma_f32_16x16x32_bf16(pf, vf, oacc[m], 0, 0, 0);
      }
      dacc = __builtin_amdgcn_mfma_f32_16x16x32_bf16(pf, onesf, dacc, 0, 0, 0);
    }
    __builtin_amdgcn_s_setprio(0);
  };

  stage(0, 0); stage(1, 64);
  asm volatile("s_waitcnt vmcnt(2)" ::: "memory");
  __builtin_amdgcn_s_barrier();
  asm volatile("" ::: "memory");
#pragma unroll 1
  for (int t = 0; t < 30; t += 3) {
#pragma unroll
    for (int j = 0; j < 3; ++j) {            // static buf ids: compute j, stage (j+2)%3
      stage((j + 2) % 3, (t + j + 2) * 64);
      compute(j);
      asm volatile("s_waitcnt vmcnt(2) lgkmcnt(0)" ::: "memory");
      __builtin_amdgcn_s_barrier();
      asm volatile("" ::: "memory");
    }
  }
  compute(0);                                 // tile 30
  asm volatile("s_waitcnt vmcnt(0) lgkmcnt(0)" ::: "memory");
  __builtin_amdgcn_s_barrier();
  asm volatile("" ::: "memory");
  compute(1);                                 // tile 31

  const int b_ = bh >> 4, hh = bh & 15;
  f32x4 rden;
#pragma unroll
  for (int r = 0; r < 4; ++r) rden[r] = __builtin_amdgcn_rcpf(dacc[r] + 1e-6f);
#pragma unroll
  for (int n = 0; n < 4; ++n) {
    const int hd = n * 16 + lr15;
#pragma unroll
    for (int r = 0; r < 4; ++r) {
      const int tt = q0 + lg * 4 + r;
      AO[((size_t)(b_ * SEQ_T + tt) << 10) + hh * 64 + hd] = f2bf(oacc[n][r] * rden[r]);
    }
  }
}

// ------------------------------------------- output projection + residual
__global__ __launch_bounds__(256) void gemm_out(
    const u16* __restrict__ A, const u16* __restrict__ W,
    const float* __restrict__ bias, const float* __restrict__ X,
    const float* __restrict__ alphap, float* __restrict__ out) {
  __shared__ u16 lds[3 * 12288];   // per buf: A 64x64 (8KB) + B 128x64 (16KB)
  const int col0 = blockIdx.x * 128, row0 = blockIdx.y * 64;
  const int tid = threadIdx.x, wv = tid >> 6, lane = tid & 63;
  const int lr15 = lane & 15, lg = lane >> 4;
  const int rA = tid >> 3, cA = tid & 7;
  const int scA = cA ^ (rA & 7);
  f32x4 acc[4][2];
#pragma unroll
  for (int m = 0; m < 4; ++m)
#pragma unroll
    for (int n = 0; n < 2; ++n) acc[m][n] = (f32x4){0.f, 0.f, 0.f, 0.f};

  auto stage = [&](int buf, int kt) {
    const int k0 = kt * 64;
    u16* base = lds + buf * 12288;
#pragma unroll
    for (int v = 0; v < 2; ++v)
      gload_lds16(A + (size_t)(row0 + v * 32 + rA) * 1024 + k0 + scA * 8,
                  base + v * 2048 + wv * 512);
#pragma unroll
    for (int v = 0; v < 4; ++v)
      gload_lds16(W + (size_t)(col0 + v * 32 + rA) * 1024 + k0 + scA * 8,
                  base + 4096 + v * 2048 + wv * 512);
  };

  auto compute = [&](int buf) {
    const u16* lA = lds + buf * 12288;
    const u16* lB = lA + 4096;
#pragma unroll
    for (int kk = 0; kk < 2; ++kk) {
      short8 a[4], b[2];
#pragma unroll
      for (int m = 0; m < 4; ++m) {
        const int row = m * 16 + lr15;
        a[m] = *(const short8*)(lA + row * 64 + (((kk * 4 + lg) ^ (row & 7)) * 8));
      }
#pragma unroll
      for (int n = 0; n < 2; ++n) {
        const int row = wv * 32 + n * 16 + lr15;
        b[n] = *(const short8*)(lB + row * 64 + (((kk * 4 + lg) ^ (row & 7)) * 8));
      }
      __builtin_amdgcn_s_setprio(1);
#pragma unroll
      for (int m = 0; m < 4; ++m)
#pragma unroll
        for (int n = 0; n < 2; ++n)
          acc[m][n] = __builtin_amdgcn_mfma_f32_16x16x32_bf16(a[m], b[n], acc[m][n], 0, 0, 0);
      __builtin_amdgcn_s_setprio(0);
    }
  };

  stage(0, 0); stage(1, 1);
  asm volatile("s_waitcnt vmcnt(6)" ::: "memory");
  __builtin_amdgcn_s_barrier();
  asm volatile("" ::: "memory");
  int cur = 0;
  for (int t = 0; t < 14; ++t) {
    stage(cur == 0 ? 2 : cur - 1, t + 2);
    compute(cur);
    __builtin_amdgcn_sched_barrier(0);
    asm volatile("s_waitcnt vmcnt(6) lgkmcnt(0)" ::: "memory");
    __builtin_amdgcn_s_barrier();
    asm volatile("" ::: "memory");
    cur = cur == 2 ? 0 : cur + 1;
  }
  compute(cur);                               // tile 14
  __builtin_amdgcn_sched_barrier(0);
  asm volatile("s_waitcnt vmcnt(0) lgkmcnt(0)" ::: "memory");
  __builtin_amdgcn_s_barrier();
  asm volatile("" ::: "memory");
  cur = cur == 2 ? 0 : cur + 1;
  compute(cur);                               // tile 15

  const float alpha = alphap[0];
#pragma unroll
  for (int n = 0; n < 2; ++n) {
    const int col = col0 + wv * 32 + n * 16 + lr15;
    const float bc = bias[col];
#pragma unroll
    for (int m = 0; m < 4; ++m) {
#pragma unroll
      for (int rr = 0; rr < 4; ++rr) {
        const int row = row0 + m * 16 + lg * 4 + rr;
        const size_t off = ((size_t)row << 10) + col;
        out[off] = X[off] + alpha * (acc[m][n][rr] + bc);
      }
    }
  }
}

// ------------------------------------------------------------------ launch
extern "C" void kernel_launch(void* const* d_in, const int* in_sizes, int n_in,
                              void* d_out, int out_size, void* d_ws, size_t ws_size,
                              hipStream_t stream) {
  const float* x  = (const float*)d_in[0];
  const float* wq = (const float*)d_in[1];
  const float* bq = (const float*)d_in[2];
  const float* wk = (const float*)d_in[3];
  const float* bk = (const float*)d_in[4];
  const float* wv = (const float*)d_in[5];
  const float* bv = (const float*)d_in[6];
  const float* wo = (const float*)d_in[7];
  const float* bo = (const float*)d_in[8];
  const float* alpha = (const float*)d_in[9];
  float* out = (float*)d_out;
  char* ws = (char*)d_ws;
  const size_t MB = 1u << 20;
  u16* xb  = (u16*)(ws + 0 * MB);
  u16* wqb = (u16*)(ws + 8 * MB);
  u16* wkb = (u16*)(ws + 10 * MB);
  u16* wvb = (u16*)(ws + 12 * MB);
  u16* wob = (u16*)(ws + 14 * MB);
  u16* qw  = (u16*)(ws + 16 * MB);   // [B,H,T,64] (scaled by -log2e/8)
  u16* kw  = (u16*)(ws + 24 * MB);   // [B,H,T,64]
  u16* vtw = (u16*)(ws + 32 * MB);   // [B,H,64,T]
  u16* aow = (u16*)(ws + 40 * MB);   // [4096,1024]

  cvt_all<<<8192, 256, 0, stream>>>(x, wq, wk, wv, wo, xb, wqb, wkb, wvb, wob);
  gemm_qkv<<<dim3(24, 32), 256, 0, stream>>>(xb, wqb, wkb, wvb, bq, bk, bv, qw, kw, vtw);
  attn_sig<<<dim3(16, 32), 512, 0, stream>>>(qw, kw, vtw, aow);
  gemm_out<<<dim3(8, 64), 256, 0, stream>>>(aow, wob, bo, x, alpha, out);
}